// Round 1
// baseline (1127.803 us; speedup 1.0000x reference)
//
#include <hip/hip_runtime.h>

#define NA   512
#define NJ   511            // NA-1
#define NF   128
#define NK   20
#define NPAIR (NA * NJ)     // 261632
#define NG   384            // 3*NF
#define KDIM 256            // 2*NF
#define BM   32             // pairs per block
#define TPB  192            // 4 tm-groups x 48 tn-groups

// ---------------- kernel 1: xp = silu(x @ phi_w^T + phi_b), (512,128) ----------------
__global__ void xp_kernel(const float* __restrict__ x,
                          const float* __restrict__ phi_w,
                          const float* __restrict__ phi_b,
                          float* __restrict__ xp) {
    __shared__ float xs[NF];
    const int i = blockIdx.x;
    const int g = threadIdx.x;
    xs[g] = x[i * NF + g];
    __syncthreads();
    float acc = phi_b[g];
    const float* wr = phi_w + g * NF;   // phi_w[g][f]
    #pragma unroll 8
    for (int f = 0; f < NF; ++f) acc = fmaf(xs[f], wr[f], acc);
    const float s = acc / (1.0f + __expf(-acc));   // silu
    xp[i * NF + g] = s;
}

// ---------------- kernel 2: owT[k][g] = o_w[g][k]  (256 x 384) ----------------
__global__ void tr_kernel(const float* __restrict__ o_w, float* __restrict__ owT) {
    const int t = blockIdx.x * 256 + threadIdx.x;   // 98304 total
    const int k = t / NG;
    const int g = t - k * NG;
    owT[t] = o_w[g * KDIM + k];
}

// ---------------- kernel 3: main fused CFConv ----------------
// Per block: 32 pairs. Phase 1 builds A[m][k] = (k<128 ? xp[i]*silu(e.w1) : xp[jj]*silu(e.w2)).
// Phase 2: C[32x384] = A[32x256] @ owT, epilogue applies (+o_b)*mask and writes split outputs.
__global__ __launch_bounds__(TPB, 3)
void main_kernel(const float* __restrict__ e,
                 const float* __restrict__ mask,
                 const float* __restrict__ w1_w, const float* __restrict__ w1_b,
                 const float* __restrict__ w2_w, const float* __restrict__ w2_b,
                 const float* __restrict__ xp,
                 const float* __restrict__ owT,
                 const float* __restrict__ o_b,
                 float* __restrict__ out) {
    __shared__ float A[BM][KDIM + 4];   // +4 pad: keeps rows off same-bank stride
    __shared__ float es[BM * NK];       // e tile, flat (contiguous copy)
    __shared__ float mk[BM];
    __shared__ int   rowi[BM];          // i per pair
    __shared__ int   rowj[BM];          // jj per pair

    const int p0 = blockIdx.x * BM;
    const int t  = threadIdx.x;

    // e tile: 32*20 = 640 contiguous floats
    for (int idx = t; idx < BM * NK; idx += TPB) es[idx] = e[p0 * NK + idx];
    if (t < BM) {
        const int p = p0 + t;
        const int i = p / NJ;
        const int j = p - i * NJ;
        rowi[t] = i;
        rowj[t] = j + (j >= i ? 1 : 0);
        mk[t]   = mask[p];
    }
    __syncthreads();

    // ---- phase 1: 32 pairs x 2 nets x 128 f = 8192 tasks ----
    for (int id = t; id < BM * KDIM; id += TPB) {
        const int m   = id >> 8;          // pair in tile
        const int net = (id >> 7) & 1;    // 0: w1 (self), 1: w2 (neighbor)
        const int f   = id & (NF - 1);
        const float* w  = (net ? w2_w : w1_w) + f * NK;
        const float* ev = es + m * NK;
        float acc = net ? w2_b[f] : w1_b[f];
        #pragma unroll
        for (int k = 0; k < NK; ++k) acc = fmaf(ev[k], w[k], acc);
        const float s = acc / (1.0f + __expf(-acc));            // silu
        const int row = net ? rowj[m] : rowi[m];
        A[m][net * NF + f] = s * xp[row * NF + f];              // mask folded into epilogue
    }
    __syncthreads();

    // ---- phase 2: register-tiled GEMM, thread = (tm, tn), micro-tile 8m x 8n ----
    const int tn = t % 48;   // 48 * 8 = 384 outputs
    const int tm = t / 48;   // 4  * 8 = 32 pairs
    float acc[8][8];
    #pragma unroll
    for (int u = 0; u < 8; ++u)
        #pragma unroll
        for (int v = 0; v < 8; ++v) acc[u][v] = 0.0f;

    const float* bbase = owT + tn * 8;
    #pragma unroll 2
    for (int k = 0; k < KDIM; ++k) {
        const float4 b0 = *(const float4*)(bbase + (size_t)k * NG);
        const float4 b1 = *(const float4*)(bbase + (size_t)k * NG + 4);
        float a[8];
        #pragma unroll
        for (int u = 0; u < 8; ++u) a[u] = A[tm * 8 + u][k];   // broadcast LDS reads
        #pragma unroll
        for (int u = 0; u < 8; ++u) {
            acc[u][0] = fmaf(a[u], b0.x, acc[u][0]);
            acc[u][1] = fmaf(a[u], b0.y, acc[u][1]);
            acc[u][2] = fmaf(a[u], b0.z, acc[u][2]);
            acc[u][3] = fmaf(a[u], b0.w, acc[u][3]);
            acc[u][4] = fmaf(a[u], b1.x, acc[u][4]);
            acc[u][5] = fmaf(a[u], b1.y, acc[u][5]);
            acc[u][6] = fmaf(a[u], b1.z, acc[u][6]);
            acc[u][7] = fmaf(a[u], b1.w, acc[u][7]);
        }
    }

    // ---- epilogue: out_seg[p*128 + (g&127)] = (acc + o_b[g]) * mask[p] ----
    const int g0  = tn * 8;
    const int seg = g0 >> 7;          // 0,1,2 -> s1,s2,s3
    const int gl  = g0 & (NF - 1);
    float ob[8];
    #pragma unroll
    for (int v = 0; v < 8; ++v) ob[v] = o_b[g0 + v];
    const size_t SEG = (size_t)NPAIR * NF;
    #pragma unroll
    for (int u = 0; u < 8; ++u) {
        const int m = tm * 8 + u;
        const float mv = mk[m];
        float* op = out + (size_t)seg * SEG + (size_t)(p0 + m) * NF + gl;
        float4 r0, r1;
        r0.x = (acc[u][0] + ob[0]) * mv;
        r0.y = (acc[u][1] + ob[1]) * mv;
        r0.z = (acc[u][2] + ob[2]) * mv;
        r0.w = (acc[u][3] + ob[3]) * mv;
        r1.x = (acc[u][4] + ob[4]) * mv;
        r1.y = (acc[u][5] + ob[5]) * mv;
        r1.z = (acc[u][6] + ob[6]) * mv;
        r1.w = (acc[u][7] + ob[7]) * mv;
        *(float4*)(op)     = r0;
        *(float4*)(op + 4) = r1;
    }
}

extern "C" void kernel_launch(void* const* d_in, const int* in_sizes, int n_in,
                              void* d_out, int out_size, void* d_ws, size_t ws_size,
                              hipStream_t stream) {
    const float* x     = (const float*)d_in[0];
    const float* e     = (const float*)d_in[1];
    const float* mask  = (const float*)d_in[2];
    // d_in[3] = loop_mask (bool) — semantics reproduced via idx math, unused
    const float* w1_w  = (const float*)d_in[4];
    const float* w1_b  = (const float*)d_in[5];
    const float* w2_w  = (const float*)d_in[6];
    const float* w2_b  = (const float*)d_in[7];
    const float* phi_w = (const float*)d_in[8];
    const float* phi_b = (const float*)d_in[9];
    const float* o_w   = (const float*)d_in[10];
    const float* o_b   = (const float*)d_in[11];
    float* out = (float*)d_out;

    float* xp  = (float*)d_ws;              // 512*128   = 65536 floats
    float* owT = xp + NA * NF;              // 256*384   = 98304 floats

    xp_kernel<<<NA, NF, 0, stream>>>(x, phi_w, phi_b, xp);
    tr_kernel<<<(KDIM * NG) / 256, 256, 0, stream>>>(o_w, owT);
    main_kernel<<<NPAIR / BM, TPB, 0, stream>>>(e, mask, w1_w, w1_b, w2_w, w2_b,
                                                xp, owT, o_b, out);
}

// Round 3
// 1026.647 us; speedup vs baseline: 1.0985x; 1.0985x over previous
//
#include <hip/hip_runtime.h>
#include <hip/hip_bf16.h>

#define NA   512
#define NJ   511            // NA-1
#define NF   128
#define NK   20
#define NPAIR (NA * NJ)     // 261632
#define NG   384            // 3*NF
#define KDIM 256            // 2*NF
#define BM   64             // pairs per block
#define TPB  512            // 8 waves: 2 (M) x 4 (N)  -- was 256: cols 192..383 never computed

using short8 = __attribute__((ext_vector_type(8))) short;
using f32x4  = __attribute__((ext_vector_type(4))) float;

// ---------------- kernel 1: xp = silu(x @ phi_w^T + phi_b), (512,128) ----------------
__global__ void xp_kernel(const float* __restrict__ x,
                          const float* __restrict__ phi_w,
                          const float* __restrict__ phi_b,
                          float* __restrict__ xp) {
    __shared__ float xs[NF];
    const int i = blockIdx.x;
    const int g = threadIdx.x;
    xs[g] = x[i * NF + g];
    __syncthreads();
    float acc = phi_b[g];
    const float* wr = phi_w + g * NF;   // phi_w[g][f]
    #pragma unroll 8
    for (int f = 0; f < NF; ++f) acc = fmaf(xs[f], wr[f], acc);
    const float s = acc / (1.0f + __expf(-acc));   // silu
    xp[i * NF + g] = s;
}

// ---------------- kernel 2: pack o_w -> bf16 in MFMA B-fragment-linear layout ----------------
// bp[((kb*24 + nf)*64 + lane)*8 + j] = bf16( o_w[ nf*16 + (lane&15) ][ kb*32 + (lane>>4)*8 + j ] )
__global__ void bpack_kernel(const float* __restrict__ o_w, ushort* __restrict__ bp) {
    const int e = blockIdx.x * 256 + threadIdx.x;   // 98304 total
    const int j    = e & 7;
    const int l    = (e >> 3) & 63;
    const int rest = e >> 9;            // 0..191
    const int nf   = rest % 24;
    const int kb   = rest / 24;
    const int g = nf * 16 + (l & 15);
    const int k = kb * 32 + (l >> 4) * 8 + j;
    __hip_bfloat16 h = __float2bfloat16(o_w[g * KDIM + k]);
    bp[e] = *reinterpret_cast<ushort*>(&h);
}

// ---------------- kernel 3: fused main ----------------
// Phase 1: A[m][k] = (k<128 ? xp[i]*silu(e.w1) : xp[jj]*silu(e.w2)) -> bf16, XOR-swizzled LDS.
// Phase 2: C[64x384] = A[64x256] @ B via mfma_f32_16x16x32_bf16; epilogue (+o_b)*mask, split write.
__global__ __launch_bounds__(TPB, 2)
void main_kernel(const float* __restrict__ e,
                 const float* __restrict__ mask,
                 const float* __restrict__ w1_w, const float* __restrict__ w1_b,
                 const float* __restrict__ w2_w, const float* __restrict__ w2_b,
                 const float* __restrict__ xp,
                 const ushort* __restrict__ bp,
                 const float* __restrict__ o_b,
                 float* __restrict__ out) {
    __shared__ short8 Ash[BM * 32];     // 64 rows x 32 granules(8 bf16) = 32 KB, swizzled
    __shared__ float  es[BM * NK];      // e tile
    __shared__ float  mk[BM];
    __shared__ int    rowi[BM];
    __shared__ int    rowj[BM];

    const int p0 = blockIdx.x * BM;
    const int t  = threadIdx.x;

    for (int idx = t; idx < BM * NK; idx += TPB) es[idx] = e[p0 * NK + idx];
    if (t < BM) {
        const int p = p0 + t;
        const int i = p / NJ;
        const int j = p - i * NJ;
        rowi[t] = i;
        rowj[t] = j + (j >= i ? 1 : 0);
        mk[t]   = mask[p];
    }
    __syncthreads();

    // ---- phase 1: 64 pairs x 32 k-granules (8 consecutive k each) = 2048 tasks ----
    for (int id = t; id < BM * 32; id += TPB) {
        const int kg  = id & 31;        // granule: k = kg*8 + j
        const int m   = id >> 5;
        const int net = kg >> 4;        // 0: w1 (self), 1: w2 (neighbor)
        const float* wmat = net ? w2_w : w1_w;
        const float* wbv  = net ? w2_b : w1_b;
        const int row = net ? rowj[m] : rowi[m];
        const float* ev = es + m * NK;
        const float* xr = xp + row * NF;
        const int f0 = (kg & 15) * 8;
        short8 pk;
        #pragma unroll
        for (int j = 0; j < 8; ++j) {
            const int f = f0 + j;
            const float* wr = wmat + f * NK;
            float acc = wbv[f];
            #pragma unroll
            for (int k = 0; k < NK; ++k) acc = fmaf(ev[k], wr[k], acc);
            const float s   = acc / (1.0f + __expf(-acc));   // silu
            const float val = s * xr[f];
            __hip_bfloat16 h = __float2bfloat16(val);
            pk[j] = *reinterpret_cast<const short*>(&h);
        }
        Ash[m * 32 + (kg ^ (m & 7))] = pk;   // swizzled granule
    }
    __syncthreads();

    // ---- phase 2: MFMA GEMM. wave grid: wm in {0,1} x 32 rows, wn in {0..3} x 96 cols ----
    const int wave = t >> 6, lane = t & 63;
    const int wm = wave & 1, wn = wave >> 1;    // 8 waves: wn in 0..3
    const int lr = lane & 15;           // A-row / B-col / C-col in fragment
    const int lk = lane >> 4;           // k-subgroup

    const f32x4 zero = {0.0f, 0.0f, 0.0f, 0.0f};
    f32x4 acc[2][6];
    #pragma unroll
    for (int mf = 0; mf < 2; ++mf)
        #pragma unroll
        for (int nf = 0; nf < 6; ++nf) acc[mf][nf] = zero;

    const short8* bpv = (const short8*)bp;
    const int r0 = wm * 32 + lr;
    const int r1 = r0 + 16;
    #pragma unroll
    for (int ks = 0; ks < 8; ++ks) {    // K = 8 steps x 32
        const int kg = ks * 4 + lk;
        const short8 a0 = Ash[r0 * 32 + (kg ^ (r0 & 7))];
        const short8 a1 = Ash[r1 * 32 + (kg ^ (r1 & 7))];
        #pragma unroll
        for (int nf = 0; nf < 6; ++nf) {
            const short8 b = bpv[((ks * 24 + wn * 6 + nf) * 64) + lane];
            acc[0][nf] = __builtin_amdgcn_mfma_f32_16x16x32_bf16(a0, b, acc[0][nf], 0, 0, 0);
            acc[1][nf] = __builtin_amdgcn_mfma_f32_16x16x32_bf16(a1, b, acc[1][nf], 0, 0, 0);
        }
    }

    // ---- epilogue: out_seg[(p0+m)*128 + (g&127)] = (acc + o_b[g]) * mask ----
    const size_t SEG = (size_t)NPAIR * NF;
    #pragma unroll
    for (int nf = 0; nf < 6; ++nf) {
        const int g   = wn * 96 + nf * 16 + lr;
        const int seg = g >> 7;
        const int gl  = g & (NF - 1);
        const float obv = o_b[g];
        float* obase = out + (size_t)seg * SEG + gl;
        #pragma unroll
        for (int mf = 0; mf < 2; ++mf) {
            const int mloc = wm * 32 + mf * 16 + lk * 4;
            #pragma unroll
            for (int r = 0; r < 4; ++r) {
                const int m = mloc + r;
                const float v = (acc[mf][nf][r] + obv) * mk[m];
                obase[(size_t)(p0 + m) * NF] = v;
            }
        }
    }
}

extern "C" void kernel_launch(void* const* d_in, const int* in_sizes, int n_in,
                              void* d_out, int out_size, void* d_ws, size_t ws_size,
                              hipStream_t stream) {
    const float* x     = (const float*)d_in[0];
    const float* e     = (const float*)d_in[1];
    const float* mask  = (const float*)d_in[2];
    // d_in[3] = loop_mask (bool) — semantics reproduced via idx math, unused
    const float* w1_w  = (const float*)d_in[4];
    const float* w1_b  = (const float*)d_in[5];
    const float* w2_w  = (const float*)d_in[6];
    const float* w2_b  = (const float*)d_in[7];
    const float* phi_w = (const float*)d_in[8];
    const float* phi_b = (const float*)d_in[9];
    const float* o_w   = (const float*)d_in[10];
    const float* o_b   = (const float*)d_in[11];
    float* out = (float*)d_out;

    float*  xp = (float*)d_ws;                      // 512*128 fp32   = 256 KB
    ushort* bpk = (ushort*)((char*)d_ws + NA * NF * 4);  // 98304 ushort = 192 KB

    xp_kernel<<<NA, NF, 0, stream>>>(x, phi_w, phi_b, xp);
    bpack_kernel<<<(8 * 24 * 64 * 8) / 256, 256, 0, stream>>>(o_w, bpk);
    main_kernel<<<NPAIR / BM, TPB, 0, stream>>>(e, mask, w1_w, w1_b, w2_w, w2_b,
                                                xp, bpk, o_b, out);
}